// Round 6
// baseline (1235.579 us; speedup 1.0000x reference)
//
#include <hip/hip_runtime.h>
#include <hip/hip_bf16.h>

#define BB 4
#define MM 50000
#define FINF 128
#define FOUTF 128
#define KCH 4
#define EE 800000
#define NROWS (BB*MM)      // 200000
#define XC 512             // columns of X = B*FIN
#define CD 512             // reduction dim = FIN*K
#define NSLICE 16          // 32-col slices of the 512 X columns
#define SL (MM*32)         // elements per slice (3.2 MB bf16)

__device__ __forceinline__ float bf2f(unsigned short u){
    union{unsigned int i; float f;} v; v.i = ((unsigned int)u) << 16; return v.f;
}
__device__ __forceinline__ unsigned short f2bf(float f){
    union{float f; unsigned int i;} v; v.f = f;
    unsigned int r = v.i + 0x7FFF + ((v.i >> 16) & 1);   // RNE
    return (unsigned short)(r >> 16);
}

typedef __bf16 bf16x8 __attribute__((ext_vector_type(8)));
typedef float  f32x4  __attribute__((ext_vector_type(4)));
typedef unsigned short u16x8 __attribute__((ext_vector_type(8)));

// X layout: slice-blocked. Global col c = b*128+f lives in slice cs = c/32 at
// X[cs*SL + m*32 + (c%32)]. 16 slices of 3.2MB; within a slice rows are 64B
// and consecutive -> spmm gathers are 64B full-seg and gemm A-frag loads are
// one contiguous 1KB segment (16 rows x 64B).

// ---- X0[cs][m][32] = bf16(x[b][m][f]) ----
__global__ __launch_bounds__(256) void k_init_x0(const float* __restrict__ x,
                                                 unsigned short* __restrict__ X0){
    int tid = blockIdx.x*256 + threadIdx.x;          // one float4 each
    if (tid >= BB*MM*FINF/4) return;
    int f4 = tid & 31;
    int t  = tid >> 5;                               // b*MM + m
    int m  = t % MM, b = t / MM;
    float4 v = ((const float4*)x)[tid];
    ushort4 o;
    o.x = f2bf(v.x); o.y = f2bf(v.y); o.z = f2bf(v.z); o.w = f2bf(v.w);
    int cs = b*4 + (f4 >> 3);
    int inner = (f4 & 7)*4;
    *(ushort4*)(X0 + (size_t)cs*SL + m*32 + inner) = o;
}

// ---- Wt swizzled into MFMA B-fragment order ----
__global__ __launch_bounds__(256) void k_prepw(const float* __restrict__ kern,
                                               unsigned short* __restrict__ Wt){
    int tid = blockIdx.x*256 + threadIdx.x;          // 65536
    int c = tid & 511, n = tid >> 9;
    int kc = c >> 7, f = c & 127;
    int ns = n >> 4, l16 = n & 15;
    int ks = c >> 5, rem = c & 31, g = rem >> 3, j = rem & 7;
    int lane = g*16 + l16;
    Wt[((ns*16 + ks)*64 + lane)*8 + j] = f2bf(kern[(f*KCH + kc)*FOUTF + n]);
}

// ---- CSR build ----
__global__ __launch_bounds__(256) void k_hist(const int* __restrict__ rows, int* __restrict__ counts){
    int e = blockIdx.x*256 + threadIdx.x;
    if (e < EE) atomicAdd(&counts[rows[e]], 1);
}

__global__ __launch_bounds__(1024) void k_scan(const int* __restrict__ counts,
                                               int* __restrict__ offs, int* __restrict__ cursor){
    __shared__ int part[1024];
    const int CH = (MM + 1023) / 1024;               // 49
    int t = threadIdx.x;
    int lo = t*CH; if (lo > MM) lo = MM;
    int hi = lo + CH; if (hi > MM) hi = MM;
    int s = 0;
    for (int i = lo; i < hi; ++i) s += counts[i];
    part[t] = s; __syncthreads();
    for (int d = 1; d < 1024; d <<= 1){
        int v = (t >= d) ? part[t-d] : 0;
        __syncthreads();
        part[t] += v;
        __syncthreads();
    }
    int run = (t == 0) ? 0 : part[t-1];
    for (int i = lo; i < hi; ++i){
        offs[i] = run; cursor[i] = run; run += counts[i];
    }
    if (t == 1023) offs[MM] = part[1023];
}

__global__ __launch_bounds__(256) void k_scatter(const int* __restrict__ rows, const int* __restrict__ cols,
                                                 const float* __restrict__ vals, int* __restrict__ cursor,
                                                 int2* __restrict__ edges){
    int e = blockIdx.x*256 + threadIdx.x;
    if (e >= EE) return;
    int r = rows[e];
    int pos = atomicAdd(&cursor[r], 1);
    int2 ev; ev.x = cols[e]; ev.y = __float_as_int(vals[e]);
    edges[pos] = ev;
}

// ---- SpMM: XCD-phased slices + edge-parallel lanes ----
// block -> (phase, xcd, rowblock of 32); slice = xcd*2+phase (3.2MB < 4MB L2).
// wave = one row at a time; lane = (e = edge slot 0..7, c = 8B col chunk 0..7).
// 2 batches of 8 edges in flight; butterfly shfl reduce over e.
__global__ __launch_bounds__(256) void k_spmm(const unsigned short* __restrict__ Xin,
                                              const unsigned short* __restrict__ Xprev,
                                              unsigned short* __restrict__ Xout,
                                              const int* __restrict__ offs,
                                              const int2* __restrict__ edges,
                                              float alpha, int sub){
    const int RB = (MM + 31) / 32;                   // 1563
    int blk   = blockIdx.x;
    int phase = blk / (8*RB);
    int rem   = blk % (8*RB);
    int xcd   = rem & 7;
    int rb    = rem >> 3;
    int slice = xcd*2 + phase;
    const unsigned short* Xs = Xin + (size_t)slice*SL;

    int wv = threadIdx.x >> 6, lane = threadIdx.x & 63;
    int e = lane >> 3, c = lane & 7;

    #pragma unroll 1
    for (int rr = 0; rr < 8; ++rr){
        int row = rb*32 + wv*8 + rr;
        if (row >= MM) return;
        int start = offs[row], end = offs[row+1];
        float a0=0.f, a1=0.f, a2=0.f, a3=0.f;
        for (int j = start; j < end; j += 16){
            int j0 = j + e, j1 = j + 8 + e;
            int2 E0 = (j0 < end) ? edges[j0] : make_int2(0, 0);
            int2 E1 = (j1 < end) ? edges[j1] : make_int2(0, 0);
            ushort4 x0 = *(const ushort4*)(Xs + (size_t)E0.x*32 + c*4);
            ushort4 x1 = *(const ushort4*)(Xs + (size_t)E1.x*32 + c*4);
            float v0 = __int_as_float(E0.y), v1 = __int_as_float(E1.y);
            a0 += v0*bf2f(x0.x) + v1*bf2f(x1.x);
            a1 += v0*bf2f(x0.y) + v1*bf2f(x1.y);
            a2 += v0*bf2f(x0.z) + v1*bf2f(x1.z);
            a3 += v0*bf2f(x0.w) + v1*bf2f(x1.w);
        }
        a0 += __shfl_xor(a0, 8);  a1 += __shfl_xor(a1, 8);
        a2 += __shfl_xor(a2, 8);  a3 += __shfl_xor(a3, 8);
        a0 += __shfl_xor(a0, 16); a1 += __shfl_xor(a1, 16);
        a2 += __shfl_xor(a2, 16); a3 += __shfl_xor(a3, 16);
        a0 += __shfl_xor(a0, 32); a1 += __shfl_xor(a1, 32);
        a2 += __shfl_xor(a2, 32); a3 += __shfl_xor(a3, 32);
        if (e == 0){
            a0 *= alpha; a1 *= alpha; a2 *= alpha; a3 *= alpha;
            size_t o = (size_t)slice*SL + (size_t)row*32 + c*4;
            if (sub){
                ushort4 pv = *(const ushort4*)(Xprev + o);
                a0 -= bf2f(pv.x); a1 -= bf2f(pv.y); a2 -= bf2f(pv.z); a3 -= bf2f(pv.w);
            }
            ushort4 ov; ov.x = f2bf(a0); ov.y = f2bf(a1); ov.z = f2bf(a2); ov.w = f2bf(a3);
            *(ushort4*)(Xout + o) = ov;
        }
    }
}

// ---- GEMM: wave tile 64x128, A-frag loads contiguous 1KB (slice layout), bf16 Y ----
__global__ __launch_bounds__(256, 2) void k_gemm(const unsigned short* __restrict__ X0,
                                                 const unsigned short* __restrict__ X1,
                                                 const unsigned short* __restrict__ X2,
                                                 const unsigned short* __restrict__ X3,
                                                 const unsigned short* __restrict__ Wt,
                                                 unsigned short* __restrict__ Y){
    const int wave = threadIdx.x >> 6;
    const int lane = threadIdx.x & 63;
    const int l16  = lane & 15;
    const int g    = lane >> 4;                       // 0..3
    const int r0   = blockIdx.x*256 + wave*64;

    int aoff[4];                                      // short-index offsets into X
    #pragma unroll
    for (int i = 0; i < 4; ++i){
        int ra = r0 + i*16 + l16;
        if (ra >= NROWS) ra = NROWS-1;
        int b = ra / MM, m = ra - b*MM;
        aoff[i] = b*4*SL + m*32 + g*8;               // + (kn&3)*SL per kstep
    }

    const unsigned short* const Xs[4] = {X0, X1, X2, X3};

    f32x4 acc[4][8];
    #pragma unroll
    for (int i = 0; i < 4; ++i)
        #pragma unroll
        for (int j = 0; j < 8; ++j) acc[i][j] = (f32x4){0.f,0.f,0.f,0.f};

    bf16x8 a_cur[4], b_cur[8], a_nxt[4], b_nxt[8];

    {   // preload ks = 0
        const unsigned short* Xb = Xs[0];
        #pragma unroll
        for (int i = 0; i < 4; ++i) a_cur[i] = *(const bf16x8*)(Xb + aoff[i]);
        #pragma unroll
        for (int ns = 0; ns < 8; ++ns) b_cur[ns] = *(const bf16x8*)(Wt + (ns*16)*512 + lane*8);
    }

    #pragma unroll
    for (int ks = 0; ks < 16; ++ks){
        if (ks < 15){
            const int kn = ks + 1;
            const unsigned short* Xb = Xs[kn >> 2];
            const int f0 = (kn & 3)*SL;
            #pragma unroll
            for (int i = 0; i < 4; ++i) a_nxt[i] = *(const bf16x8*)(Xb + aoff[i] + f0);
            #pragma unroll
            for (int ns = 0; ns < 8; ++ns) b_nxt[ns] = *(const bf16x8*)(Wt + (ns*16 + kn)*512 + lane*8);
        }
        #pragma unroll
        for (int ns = 0; ns < 8; ++ns)
            #pragma unroll
            for (int i = 0; i < 4; ++i)
                acc[i][ns] = __builtin_amdgcn_mfma_f32_16x16x32_bf16(a_cur[i], b_cur[ns], acc[i][ns], 0, 0, 0);
        #pragma unroll
        for (int i = 0; i < 4; ++i) a_cur[i] = a_nxt[i];
        #pragma unroll
        for (int ns = 0; ns < 8; ++ns) b_cur[ns] = b_nxt[ns];
    }

    #pragma unroll
    for (int i = 0; i < 4; ++i){
        #pragma unroll
        for (int reg = 0; reg < 4; ++reg){
            int r = r0 + i*16 + g*4 + reg;
            if (r < NROWS){
                #pragma unroll
                for (int ns = 0; ns < 8; ++ns){
                    float v = acc[i][ns][reg];
                    Y[(size_t)r*FOUTF + ns*16 + l16] = f2bf(v > 0.f ? v : 0.f);
                }
            }
        }
    }
}

// ---- column sums of bf16 Y per batch: grid (256 chunks, B), 256 thr ----
__global__ __launch_bounds__(256) void k_colmean(const unsigned short* __restrict__ Y,
                                                 float* __restrict__ sacc){
    int b = blockIdx.y, t = threadIdx.x;
    int c8 = t & 15, rs = t >> 4;                    // 16 col-chunks x 16 row-groups
    const int rows = (MM + gridDim.x - 1) / gridDim.x;
    int m0 = blockIdx.x * rows;
    int mend = m0 + rows; if (mend > MM) mend = MM;
    float a[8];
    #pragma unroll
    for (int i = 0; i < 8; ++i) a[i] = 0.f;
    for (int m = m0 + rs; m < mend; m += 16){
        u16x8 v = *(const u16x8*)(Y + ((size_t)b*MM + m)*FOUTF + c8*8);
        #pragma unroll
        for (int i = 0; i < 8; ++i) a[i] += bf2f(v[i]);
    }
    __shared__ float red[16][16][8];
    #pragma unroll
    for (int i = 0; i < 8; ++i) red[rs][c8][i] = a[i];
    __syncthreads();
    if (t < 16){
        float s[8];
        #pragma unroll
        for (int i = 0; i < 8; ++i) s[i] = 0.f;
        for (int r2 = 0; r2 < 16; ++r2)
            #pragma unroll
            for (int i = 0; i < 8; ++i) s[i] += red[r2][t][i];
        #pragma unroll
        for (int i = 0; i < 8; ++i) atomicAdd(&sacc[b*FOUTF + t*8 + i], s[i]);
    }
}

// ---- SE MLP: u = sigmoid(swish(mean @ Wd + bd) @ Wu + bu) ----
__global__ __launch_bounds__(128) void k_se(const float* __restrict__ sacc,
                                            const float* __restrict__ Wd, const float* __restrict__ bd,
                                            const float* __restrict__ Wu, const float* __restrict__ bu,
                                            float* __restrict__ u){
    int b = blockIdx.x, t = threadIdx.x;
    __shared__ float sm[128];
    __shared__ float dsh[16];
    sm[t] = sacc[b*FOUTF + t] * (1.0f/MM);
    __syncthreads();
    if (t < 16){
        float a = bd[t];
        for (int f = 0; f < 128; ++f) a += sm[f]*Wd[f*16 + t];
        dsh[t] = a / (1.f + expf(-a));                // swish
    }
    __syncthreads();
    float a = bu[t];
    for (int j = 0; j < 16; ++j) a += dsh[j]*Wu[j*FOUTF + t];
    u[b*FOUTF + t] = 1.f/(1.f + expf(-a));
}

// ---- out = bf16 Y * u[b] (f32 out) ----
__global__ __launch_bounds__(256) void k_scale(const unsigned short* __restrict__ Y,
                                               const float* __restrict__ u,
                                               float* __restrict__ out){
    int tid = blockIdx.x*256 + threadIdx.x;          // one u16x8 each
    if (tid >= NROWS*FOUTF/8) return;
    int b  = tid / (MM*FOUTF/8);
    int f8 = tid & 15;
    u16x8 yv = ((const u16x8*)Y)[tid];
    const float* up = u + b*FOUTF + f8*8;
    float4 o0, o1;
    o0.x = bf2f(yv[0])*up[0]; o0.y = bf2f(yv[1])*up[1];
    o0.z = bf2f(yv[2])*up[2]; o0.w = bf2f(yv[3])*up[3];
    o1.x = bf2f(yv[4])*up[4]; o1.y = bf2f(yv[5])*up[5];
    o1.z = bf2f(yv[6])*up[6]; o1.w = bf2f(yv[7])*up[7];
    ((float4*)out)[tid*2]   = o0;
    ((float4*)out)[tid*2+1] = o1;
}

extern "C" void kernel_launch(void* const* d_in, const int* in_sizes, int n_in,
                              void* d_out, int out_size, void* d_ws, size_t ws_size,
                              hipStream_t stream){
    (void)in_sizes; (void)n_in; (void)out_size; (void)ws_size;
    const float* x    = (const float*)d_in[0];
    const float* lv   = (const float*)d_in[1];
    const int*   lr   = (const int*)d_in[2];
    const int*   lc   = (const int*)d_in[3];
    const float* kern = (const float*)d_in[4];
    const float* Wd   = (const float*)d_in[5];
    const float* bd   = (const float*)d_in[6];
    const float* Wu   = (const float*)d_in[7];
    const float* bu   = (const float*)d_in[8];
    float* out = (float*)d_out;

    char* w = (char*)d_ws;
    size_t off = 0;
    auto take = [&](size_t bytes)->char*{
        char* p = w + off; off += (bytes + 255) & ~(size_t)255; return p;
    };
    unsigned short* X[4];
    for (int i = 0; i < 4; ++i) X[i] = (unsigned short*)take((size_t)MM*XC*2);
    unsigned short* Y  = (unsigned short*)take((size_t)NROWS*FOUTF*2);
    unsigned short* Wt = (unsigned short*)take((size_t)FOUTF*CD*2);
    int* counts        = (int*)take((size_t)MM*4);
    int* offs          = (int*)take((size_t)(MM+1)*4);
    int* cursor        = (int*)take((size_t)MM*4);
    int2* edges        = (int2*)take((size_t)EE*8);
    float* sacc        = (float*)take((size_t)BB*FOUTF*4);
    float* u           = (float*)take((size_t)BB*FOUTF*4);

    hipMemsetAsync(counts, 0, MM*4, stream);
    hipMemsetAsync(sacc, 0, BB*FOUTF*4, stream);

    k_init_x0<<<25000, 256, 0, stream>>>(x, X[0]);
    k_prepw<<<256, 256, 0, stream>>>(kern, Wt);
    k_hist<<<(EE+255)/256, 256, 0, stream>>>(lr, counts);
    k_scan<<<1, 1024, 0, stream>>>(counts, offs, cursor);
    k_scatter<<<(EE+255)/256, 256, 0, stream>>>(lr, lc, lv, cursor, edges);

    const int RB = (MM + 31) / 32;                   // 1563
    const int SPMM_GRID = RB * 16;                   // 25008 (2 phases x 8 xcd x RB)
    k_spmm<<<SPMM_GRID, 256, 0, stream>>>(X[0], X[0], X[1], offs, edges, 1.0f, 0);
    k_spmm<<<SPMM_GRID, 256, 0, stream>>>(X[1], X[0], X[2], offs, edges, 2.0f, 1);
    k_spmm<<<SPMM_GRID, 256, 0, stream>>>(X[2], X[1], X[3], offs, edges, 2.0f, 1);

    k_gemm<<<(NROWS+255)/256, 256, 0, stream>>>(X[0], X[1], X[2], X[3], Wt, Y);

    dim3 gmean(256, BB);
    k_colmean<<<gmean, 256, 0, stream>>>(Y, sacc);
    k_se<<<BB, 128, 0, stream>>>(sacc, Wd, bd, Wu, bu, u);
    k_scale<<<12500, 256, 0, stream>>>(Y, u, out);
}